// Round 13
// baseline (87.758 us; speedup 1.0000x reference)
//
#include <hip/hip_runtime.h>
#include <math.h>

#define N_EXP 64
#define TOPK 8
#define TOPK_G 4
#define D_DIM 2048
#define S_TOT 16384
#define ROWS_PER_BLOCK 16

typedef _Float16 half8 __attribute__((ext_vector_type(8)));
typedef float f32x4 __attribute__((ext_vector_type(4)));

// kernel 0: split W fp32 -> (Wh, Wl*2^11) fp16. 131072 elems.
__global__ void split_w_kernel(const float* __restrict__ W,
                               _Float16* __restrict__ Wh,
                               _Float16* __restrict__ Wl) {
    int t = blockIdx.x * blockDim.x + threadIdx.x;
    if (t < N_EXP * D_DIM) {
        float f = W[t];
        _Float16 h = (_Float16)f;
        Wh[t] = h;
        Wl[t] = (_Float16)((f - (float)h) * 2048.0f);
    }
}

// kernel 1: fused fp16x3 MFMA router. Block = 16 rows, 4 waves = 4-way K
// split (512 k each). Per wave: A-frag = x[m=lane&15][8k at (lane>>4)*8]
// (global->reg->cvt, no LDS in K-loop); B-frag = Wh/Wl[e=ct*16+lane&15]
// [same 8k] = one 16B load (L2-resident). 12 MFMA/k-step:
// acc_HH += xh*wh ; acc_HL += xh*wl ; acc_LH += xl*wh.
// logit = HH + (HL+LH)*2^-11. 4-way LDS reduce, sigmoid, R7-proven select.
__launch_bounds__(256)
__global__ void router_kernel(const float* __restrict__ x,
                              const _Float16* __restrict__ Wh,
                              const _Float16* __restrict__ Wl,
                              const float* __restrict__ bias,
                              float* __restrict__ out_idx,
                              float* __restrict__ out_w)
{
    __shared__ float lg[ROWS_PER_BLOCK * 68];
    __shared__ float bs[N_EXP];

    const int tid  = threadIdx.x;
    const int wave = tid >> 6;        // = k-quarter 0..3
    const int lane = tid & 63;
    const int m16  = lane & 15;       // A row within tile / B expert within ct
    const int kb   = lane >> 4;       // k sub-block 0..3
    const int row0 = blockIdx.x * ROWS_PER_BLOCK;

    if (tid < N_EXP) bs[tid] = bias[tid];

    f32x4 accHH[4], accHL[4], accLH[4];
#pragma unroll
    for (int ct = 0; ct < 4; ++ct) {
        accHH[ct] = (f32x4)0.0f; accHL[ct] = (f32x4)0.0f; accLH[ct] = (f32x4)0.0f;
    }

    const float* xc = x + (size_t)(row0 + m16) * D_DIM + wave * 512 + kb * 8;
    const _Float16* bhc = Wh + (size_t)m16 * D_DIM + wave * 512 + kb * 8;
    const _Float16* blc = Wl + (size_t)m16 * D_DIM + wave * 512 + kb * 8;

    float4 a0 = *(const float4*)(xc);
    float4 a1 = *(const float4*)(xc + 4);

    for (int ks = 0; ks < 16; ++ks) {
        // issue B loads (L2) and next A loads (HBM) early
        half8 bh[4], bl[4];
#pragma unroll
        for (int ct = 0; ct < 4; ++ct) {
            bh[ct] = *(const half8*)(bhc + (size_t)ct * 16 * D_DIM + ks * 32);
            bl[ct] = *(const half8*)(blc + (size_t)ct * 16 * D_DIM + ks * 32);
        }
        float4 na0, na1;
        if (ks + 1 < 16) {
            na0 = *(const float4*)(xc + 32);
            na1 = *(const float4*)(xc + 36);
        }
        // split x into hi + scaled-lo fp16 (exact residual: Sterbenz)
        half8 xh, xl;
        {
            const float v[8] = {a0.x, a0.y, a0.z, a0.w, a1.x, a1.y, a1.z, a1.w};
#pragma unroll
            for (int i = 0; i < 8; ++i) {
                _Float16 h = (_Float16)v[i];
                xh[i] = h;
                xl[i] = (_Float16)((v[i] - (float)h) * 2048.0f);
            }
        }
#pragma unroll
        for (int ct = 0; ct < 4; ++ct) {
            accHH[ct] = __builtin_amdgcn_mfma_f32_16x16x32_f16(xh, bh[ct], accHH[ct], 0, 0, 0);
            accHL[ct] = __builtin_amdgcn_mfma_f32_16x16x32_f16(xh, bl[ct], accHL[ct], 0, 0, 0);
            accLH[ct] = __builtin_amdgcn_mfma_f32_16x16x32_f16(xl, bh[ct], accLH[ct], 0, 0, 0);
        }
        if (ks + 1 < 16) { a0 = na0; a1 = na1; xc += 32; }
    }

    // combine terms + 4-way cross-wave reduction (serialized adds, 4 barriers)
    const float inv2048 = 1.0f / 2048.0f;
    for (int ph = 0; ph < 4; ++ph) {
        if (wave == ph) {
#pragma unroll
            for (int ct = 0; ct < 4; ++ct) {
#pragma unroll
                for (int r = 0; r < 4; ++r) {
                    const float val = accHH[ct][r] + (accHL[ct][r] + accLH[ct][r]) * inv2048;
                    const int idx = (kb * 4 + r) * 68 + ct * 16 + m16;  // D: row=(lane>>4)*4+r, col=lane&15
                    if (ph == 0) lg[idx] = val;
                    else         lg[idx] += val;
                }
            }
        }
        __syncthreads();
    }

    // sigmoid in place
    if (tid < ROWS_PER_BLOCK * 8) {
        const int rg = tid >> 3, sl = tid & 7;
#pragma unroll
        for (int j = 0; j < 8; ++j) {
            const int idx = rg * 68 + sl * 8 + j;
            lg[idx] = 1.0f / (1.0f + expf(-lg[idx]));
        }
    }
    __syncthreads();

    // grouped top-k: R7-proven parallel selection (8 sublanes per row)
    if (tid < ROWS_PER_BLOCK * 8) {
        const int rg = tid >> 3;
        const int sl = tid & 7;
        const int row = row0 + rg;

        float bsc[8];
        float gm = -INFINITY;
#pragma unroll
        for (int j = 0; j < 8; ++j) {
            bsc[j] = lg[rg * 68 + sl * 8 + j] + bs[sl * 8 + j];
            gm = fmaxf(gm, bsc[j]);
        }

        int grank = 0;
#pragma unroll
        for (int s = 1; s < 8; ++s) {
            float og = __shfl_xor(gm, s, 8);
            int   osl = sl ^ s;
            if (og > gm || (og == gm && osl < sl)) ++grank;
        }
        unsigned alive = (grank < TOPK_G) ? 0xFFu : 0u;

        float wsum = 0.f;
        float myw = 0.f;
        const int orow = row * TOPK;
        for (int k = 0; k < TOPK; ++k) {
            float bv = -INFINITY; int be = 9999;
#pragma unroll
            for (int j = 0; j < 8; ++j) {
                if (alive & (1u << j)) {
                    if (bsc[j] > bv) { bv = bsc[j]; be = sl * 8 + j; }
                }
            }
#pragma unroll
            for (int s = 1; s < 8; s <<= 1) {
                float ov = __shfl_xor(bv, s, 8);
                int   oe = __shfl_xor(be, s, 8);
                if (ov > bv || (ov == bv && oe < be)) { bv = ov; be = oe; }
            }
            const float wr = lg[rg * 68 + be];   // broadcast read of sigmoid score
            wsum += wr;
            if ((be >> 3) == sl) alive &= ~(1u << (be & 7));
            if (sl == k) { out_idx[orow + k] = (float)be; myw = wr; }
        }
        const float inv = 1.0f / (wsum + 1e-20f);
        out_w[orow + sl] = myw * inv;
    }
}

extern "C" void kernel_launch(void* const* d_in, const int* in_sizes, int n_in,
                              void* d_out, int out_size, void* d_ws, size_t ws_size,
                              hipStream_t stream) {
    const float* x    = (const float*)d_in[0];
    const float* W    = (const float*)d_in[1];
    const float* bias = (const float*)d_in[2];
    float* out = (float*)d_out;

    _Float16* Wh = (_Float16*)d_ws;                      // 256 KB
    _Float16* Wl = (_Float16*)((char*)d_ws + 262144);    // 256 KB

    hipLaunchKernelGGL(split_w_kernel, dim3((N_EXP * D_DIM + 255) / 256), dim3(256),
                       0, stream, W, Wh, Wl);
    hipLaunchKernelGGL(router_kernel, dim3(S_TOT / ROWS_PER_BLOCK), dim3(256),
                       0, stream, x, Wh, Wl, bias, out, out + S_TOT * TOPK);
}

// Round 14
// 87.263 us; speedup vs baseline: 1.0057x; 1.0057x over previous
//
#include <hip/hip_runtime.h>
#include <math.h>

#define N_EXP 64
#define TOPK 8
#define TOPK_G 4
#define D_DIM 2048
#define S_TOT 16384
#define ROWS_PER_BLOCK 16

typedef _Float16 half8 __attribute__((ext_vector_type(8)));
typedef float f32x4 __attribute__((ext_vector_type(4)));

// kernel 0: split W fp32 -> (Wh, Wl*2^11) fp16. 131072 elems.
__global__ void split_w_kernel(const float* __restrict__ W,
                               _Float16* __restrict__ Wh,
                               _Float16* __restrict__ Wl) {
    int t = blockIdx.x * blockDim.x + threadIdx.x;
    if (t < N_EXP * D_DIM) {
        float f = W[t];
        _Float16 h = (_Float16)f;
        Wh[t] = h;
        Wl[t] = (_Float16)((f - (float)h) * 2048.0f);
    }
}

// kernel 1: fused fp16x3 MFMA router (R13-proven numerics: absmax 4.9e-4).
// ONLY change vs R13: k-loop FULLY UNROLLED, loads straight-line so the
// compiler can software-pipeline them (R13's rolled loop serialized ~10
// loads x ~400cy L2 latency per k-step = the 4000 cy/ks stall).
__launch_bounds__(256)
__global__ void router_kernel(const float* __restrict__ x,
                              const _Float16* __restrict__ Wh,
                              const _Float16* __restrict__ Wl,
                              const float* __restrict__ bias,
                              float* __restrict__ out_idx,
                              float* __restrict__ out_w)
{
    __shared__ float lg[ROWS_PER_BLOCK * 68];
    __shared__ float bs[N_EXP];

    const int tid  = threadIdx.x;
    const int wave = tid >> 6;        // = k-quarter 0..3
    const int lane = tid & 63;
    const int m16  = lane & 15;       // A row within tile / B expert within ct
    const int kb   = lane >> 4;       // k sub-block 0..3
    const int row0 = blockIdx.x * ROWS_PER_BLOCK;

    if (tid < N_EXP) bs[tid] = bias[tid];

    f32x4 accHH[4], accHL[4], accLH[4];
#pragma unroll
    for (int ct = 0; ct < 4; ++ct) {
        accHH[ct] = (f32x4)0.0f; accHL[ct] = (f32x4)0.0f; accLH[ct] = (f32x4)0.0f;
    }

    const float* xc = x + (size_t)(row0 + m16) * D_DIM + wave * 512 + kb * 8;
    const _Float16* bhc = Wh + (size_t)m16 * D_DIM + wave * 512 + kb * 8;
    const _Float16* blc = Wl + (size_t)m16 * D_DIM + wave * 512 + kb * 8;

#pragma unroll
    for (int ks = 0; ks < 16; ++ks) {
        // straight-line after unroll: compiler hoists these to available depth
        float4 a0 = *(const float4*)(xc + ks * 32);
        float4 a1 = *(const float4*)(xc + ks * 32 + 4);
        half8 bh[4], bl[4];
#pragma unroll
        for (int ct = 0; ct < 4; ++ct) {
            bh[ct] = *(const half8*)(bhc + (size_t)ct * 16 * D_DIM + ks * 32);
            bl[ct] = *(const half8*)(blc + (size_t)ct * 16 * D_DIM + ks * 32);
        }
        // split x into hi + scaled-lo fp16 (exact residual)
        half8 xh, xl;
        {
            const float v[8] = {a0.x, a0.y, a0.z, a0.w, a1.x, a1.y, a1.z, a1.w};
#pragma unroll
            for (int i = 0; i < 8; ++i) {
                _Float16 h = (_Float16)v[i];
                xh[i] = h;
                xl[i] = (_Float16)((v[i] - (float)h) * 2048.0f);
            }
        }
#pragma unroll
        for (int ct = 0; ct < 4; ++ct) {
            accHH[ct] = __builtin_amdgcn_mfma_f32_16x16x32_f16(xh, bh[ct], accHH[ct], 0, 0, 0);
            accHL[ct] = __builtin_amdgcn_mfma_f32_16x16x32_f16(xh, bl[ct], accHL[ct], 0, 0, 0);
            accLH[ct] = __builtin_amdgcn_mfma_f32_16x16x32_f16(xl, bh[ct], accLH[ct], 0, 0, 0);
        }
    }

    // combine terms + 4-way cross-wave reduction (serialized adds, 4 barriers)
    const float inv2048 = 1.0f / 2048.0f;
    for (int ph = 0; ph < 4; ++ph) {
        if (wave == ph) {
#pragma unroll
            for (int ct = 0; ct < 4; ++ct) {
#pragma unroll
                for (int r = 0; r < 4; ++r) {
                    const float val = accHH[ct][r] + (accHL[ct][r] + accLH[ct][r]) * inv2048;
                    const int idx = (kb * 4 + r) * 68 + ct * 16 + m16;  // D: row=(lane>>4)*4+r, col=lane&15
                    if (ph == 0) lg[idx] = val;
                    else         lg[idx] += val;
                }
            }
        }
        __syncthreads();
    }

    // sigmoid in place
    if (tid < ROWS_PER_BLOCK * 8) {
        const int rg = tid >> 3, sl = tid & 7;
#pragma unroll
        for (int j = 0; j < 8; ++j) {
            const int idx = rg * 68 + sl * 8 + j;
            lg[idx] = 1.0f / (1.0f + expf(-lg[idx]));
        }
    }
    __syncthreads();

    // grouped top-k: R7-proven parallel selection (8 sublanes per row)
    if (tid < ROWS_PER_BLOCK * 8) {
        const int rg = tid >> 3;
        const int sl = tid & 7;
        const int row = row0 + rg;

        float bsc[8];
        float gm = -INFINITY;
#pragma unroll
        for (int j = 0; j < 8; ++j) {
            bsc[j] = lg[rg * 68 + sl * 8 + j] + bs[sl * 8 + j];
            gm = fmaxf(gm, bsc[j]);
        }

        int grank = 0;
#pragma unroll
        for (int s = 1; s < 8; ++s) {
            float og = __shfl_xor(gm, s, 8);
            int   osl = sl ^ s;
            if (og > gm || (og == gm && osl < sl)) ++grank;
        }
        unsigned alive = (grank < TOPK_G) ? 0xFFu : 0u;

        float wsum = 0.f;
        float myw = 0.f;
        const int orow = row * TOPK;
        for (int k = 0; k < TOPK; ++k) {
            float bv = -INFINITY; int be = 9999;
#pragma unroll
            for (int j = 0; j < 8; ++j) {
                if (alive & (1u << j)) {
                    if (bsc[j] > bv) { bv = bsc[j]; be = sl * 8 + j; }
                }
            }
#pragma unroll
            for (int s = 1; s < 8; s <<= 1) {
                float ov = __shfl_xor(bv, s, 8);
                int   oe = __shfl_xor(be, s, 8);
                if (ov > bv || (ov == bv && oe < be)) { bv = ov; be = oe; }
            }
            const float wr = lg[rg * 68 + be];   // broadcast read of sigmoid score
            wsum += wr;
            if ((be >> 3) == sl) alive &= ~(1u << (be & 7));
            if (sl == k) { out_idx[orow + k] = (float)be; myw = wr; }
        }
        const float inv = 1.0f / (wsum + 1e-20f);
        out_w[orow + sl] = myw * inv;
    }
}

extern "C" void kernel_launch(void* const* d_in, const int* in_sizes, int n_in,
                              void* d_out, int out_size, void* d_ws, size_t ws_size,
                              hipStream_t stream) {
    const float* x    = (const float*)d_in[0];
    const float* W    = (const float*)d_in[1];
    const float* bias = (const float*)d_in[2];
    float* out = (float*)d_out;

    _Float16* Wh = (_Float16*)d_ws;                      // 256 KB
    _Float16* Wl = (_Float16*)((char*)d_ws + 262144);    // 256 KB

    hipLaunchKernelGGL(split_w_kernel, dim3((N_EXP * D_DIM + 255) / 256), dim3(256),
                       0, stream, W, Wh, Wl);
    hipLaunchKernelGGL(router_kernel, dim3(S_TOT / ROWS_PER_BLOCK), dim3(256),
                       0, stream, x, Wh, Wl, bias, out, out + S_TOT * TOPK);
}